// Round 2
// baseline (379.045 us; speedup 1.0000x reference)
//
#include <hip/hip_runtime.h>

// Radon transform, MI355X. B=4, IMG=256, NA=512.
// R1: slab-sequential blocks. Each block owns (batch, 2 contiguous angles) and
// loops over 8 row-slabs, restaging each into LDS (fp16 tap-pairs) and carrying
// the ray accumulator in registers -> NO atomics, NO zero kernel, one plain
// store per ray. 1024 blocks x 512 thr, 38.9 KB LDS -> 4 blocks/CU = 32 waves/CU.

typedef _Float16 f16;
typedef _Float16 f16x2 __attribute__((ext_vector_type(2)));

#define WST   263                 // LDS row stride in 4B words (odd -> bank decorrelation)
#define SROWS 37                  // staged padded rows per slab (32 + margins)
#define LDSW  (SROWS * WST)       // 9731 words = 38,924 B

// one bilinear sample from the staged slab; 2x ds_read_b32, packed f16 lerp
#define SAMPLE(HF, ACC) do {                                   \
    float px_  = fmaf((HF), sth, Ax2);                         \
    float pyr_ = fmaf((HF), cth, Ayr);                         \
    int   xi_  = (int)px_;                                     \
    int   rr_  = (int)pyr_;                                    \
    float wx_  = px_  - (float)xi_;                            \
    float wy_  = pyr_ - (float)rr_;                            \
    int   e_   = rr_ * WST + xi_;                              \
    f16x2 p0_  = lds2[e_];                                     \
    f16x2 p1_  = lds2[e_ + WST];                               \
    f16   wyh_ = (f16)wy_;                                     \
    f16x2 wy2_ = {wyh_, wyh_};                                 \
    f16x2 t_   = p0_ + wy2_ * (p1_ - p0_);                     \
    float t0_  = (float)t_.x, t1_ = (float)t_.y;               \
    (ACC) += fmaf(wx_, t1_ - t0_, t0_);                        \
} while (0)

__global__ __launch_bounds__(512, 8) void radon_kernel(const float* __restrict__ img,
                                                       float* __restrict__ out) {
    __shared__ f16x2 lds2[LDSW];
    const int tid = threadIdx.x;
    const int bx  = blockIdx.x;           // 1024 blocks = b(4) x ag(256)
    const int ag  = bx & 255;             // angle pair
    const int b   = bx >> 8;              // batch
    const int w   = tid & 255;            // detector cell
    const int sub = tid >> 8;             // which angle of the pair (one per 4-wave half)
    const int a   = (ag << 1) + sub;

    const float* im = img + (b << 16);

    float sth, cth;
    sincosf((float)a * 6.1359231515425649e-3f, &sth, &cth);   // theta = a*pi/512
    const float xw  = (float)w - 127.5f;
    // fx(h) = Ax + h*sth, fy(h) = Ay + h*cth  (pixel coords, align_corners=True)
    const float Ax  = fmaf(cth, xw, fmaf(sth, -127.5f, 127.5f));
    const float Ay  = fmaf(-sth, xw, fmaf(cth, -127.5f, 127.5f));
    const float invc = 1.0f / cth;        // |cth| >= ~3e-8, never 0
    const float Ax2  = Ax + 2.0f;         // LDS col offset (pad 2)

    // ---- q-independent x-validity interval (widened <=1; LDS zero cols absorb slack)
    int hx0 = 0, hx1 = 255;
    if (sth >= 1e-6f) {
        const float invs = 1.0f / sth;    // sth >= 0 on [0, pi)
        float t0 = (-1.0f - Ax) * invs;
        float t1 = (256.0f - Ax) * invs;
        t0 = fmaxf(fminf(t0, 400.0f), -400.0f);
        t1 = fmaxf(fminf(t1, 400.0f), -400.0f);
        hx0 = max(0,   (int)floorf(t0));
        hx1 = min(255, (int)ceilf(t1));
    } else if (Ax <= -1.0f || Ax >= 256.0f) {
        hx1 = -1;                         // fx constant & out of range: ray is empty
    }

    float acc = 0.0f;

    for (int q = 0; q < 8; ++q) {
        if (q) __syncthreads();           // previous slab's compute done before restage
        const int rbase = (q << 5) - 2;   // first staged image row (pad margin 2)

        // ---- stage slab: word u=(rr,x) = (P[r][x-2], P[r][x-1]) fp16x2, P=0 outside
        for (int u = tid; u < LDSW; u += 512) {
            int rr = u / WST;
            int x  = u - rr * WST;
            int r  = rbase + rr;
            int c0 = x - 2;
            float va = 0.f, vb = 0.f;
            if ((unsigned)r < 256u) {
                const float* rp = im + (r << 8);
                if ((unsigned)c0 < 256u)       va = rp[c0];
                if ((unsigned)(c0 + 1) < 256u) vb = rp[c0 + 1];
            }
            f16x2 h2; h2.x = (f16)va; h2.y = (f16)vb;
            lds2[u] = h2;
        }
        __syncthreads();

        // ---- y-ownership: exact ceil-partition across slabs (identical floats in
        // adjacent q -> no gaps/overlaps); outer slabs extended over the zero halo
        const float B0f = (q == 0) ? -1.25f  : (float)(q << 5);
        const float B1f = (q == 7) ? 257.25f : (float)((q << 5) + 32);
        float tA = (B0f - Ay) * invc;
        float tB = (B1f - Ay) * invc;
        float ylo = fminf(tA, tB), yhi = fmaxf(tA, tB);
        ylo = fmaxf(fminf(ylo, 400.0f), -400.0f);
        yhi = fmaxf(fminf(yhi, 400.0f), -400.0f);
        int h0 = max((int)ceilf(ylo), hx0);
        int h1 = min((int)ceilf(yhi) - 1, hx1);
        if (h0 > h1) continue;            // all threads still reach next-q barrier

        const float Ayr = Ay - (float)rbase;   // LDS row coord base, in [0.7, 35.3]
        float acc0 = 0.f, acc1 = 0.f;
        float hfa = (float)h0, hfb = hfa + 1.0f;
        const int n = h1 - h0 + 1;
        int i = 0;
        for (; i + 2 <= n; i += 2) {      // x2 unroll: two independent samples in flight
            SAMPLE(hfa, acc0);
            SAMPLE(hfb, acc1);
            hfa += 2.0f; hfb += 2.0f;
        }
        if (i < n) SAMPLE(hfa, acc0);
        acc += acc0 + acc1;
    }

    out[(b << 17) + (w << 9) + a] = acc;  // out[b,0,w,a], plain store
}

extern "C" void kernel_launch(void* const* d_in, const int* in_sizes, int n_in,
                              void* d_out, int out_size, void* d_ws, size_t ws_size,
                              hipStream_t stream) {
    const float* img = (const float*)d_in[0];
    float* out = (float*)d_out;
    radon_kernel<<<dim3(1024), dim3(512), 0, stream>>>(img, out);
}

// Round 5
// 162.443 us; speedup vs baseline: 2.3334x; 2.3334x over previous
//
#include <hip/hip_runtime.h>

// Radon transform, MI355X. B=4, IMG=256, NA=512.
// R5 = R4 + pc clamp to [0, 256.999] in SAMP. Fixes the trunc-vs-floor
// mismatch at the v=-1 edge ((int) truncates, fractf floors -> full-weight
// garbage tap when FP rounding pushes pc to -1e-5) and the v=256 edge
// (e-clamp previously aliased to a garbage word at full weight).
// Structure (R3): slab-parallel blocks (stage once / 8 angles) + adaptive slab
// orientation (row-slabs for a<128|a>=384, column-slabs from a transposed copy
// otherwise) -> per-slab ray length <= 46 for every angle. Partials ->
// ws[q][b][a][w] (wave-coalesced plain stores), reduced by a transpose-reduce
// kernel. Inner loop: column-major LDS (pair-words vertically adjacent ->
// 1 ds_read2_b32), v_fract fractions, v_cvt_pkrtz + v_dot2_f32_f16 epilogue.

typedef _Float16 f16;
typedef _Float16 f16x2 __attribute__((ext_vector_type(2)));
typedef __fp16   h16x2 __attribute__((ext_vector_type(2)));

#define SR    37            // staged slab rows (32 + margins), odd
#define NC    257           // staged pair-columns X = 0..256
#define LDSW  (NC * SR)     // 9509 f16x2 words = 38,036 B -> 4 blocks/CU
#define EMAX  (LDSW - 2)

// one bilinear sample: word (X,rr) = (P[r][X-1], P[r][X]); words e,e+1 are
// vertical neighbors -> single ds_read2_b32; fdot2 does x-lerp + f32 acc.
#define SAMP(PC, PR, ACC) do {                                  \
    float pc_ = fminf(fmaxf((PC), 0.0f), 256.999f);             \
    float pr_ = (PR);                                           \
    int   Xi_ = (int)pc_;                                       \
    int   Ri_ = (int)pr_;                                       \
    float wc_ = __builtin_amdgcn_fractf(pc_);                   \
    float wr_ = __builtin_amdgcn_fractf(pr_);                   \
    int   e_  = Xi_ * SR + Ri_;                                 \
    e_ = min(e_, EMAX);                                         \
    f16x2 p0_ = lds2[e_];                                       \
    f16x2 p1_ = lds2[e_ + 1];                                   \
    f16   wrh_ = (f16)wr_;                                      \
    f16x2 wv_  = {wrh_, wrh_};                                  \
    f16x2 t_   = p0_ + wv_ * (p1_ - p0_);                       \
    h16x2 wp_  = __builtin_amdgcn_cvt_pkrtz(1.0f - wc_, wc_);   \
    (ACC) = __builtin_amdgcn_fdot2(__builtin_bit_cast(h16x2, t_), wp_, (ACC), false); \
} while (0)

__global__ __launch_bounds__(256) void transpose_k(const float* __restrict__ img,
                                                   float* __restrict__ imT) {
    __shared__ float tl[32][33];
    const int bx = blockIdx.x;                    // 256 = b(4) x ty(8) x tx(8)
    const int x0 = (bx & 7) << 5, y0 = ((bx >> 3) & 7) << 5, b = bx >> 6;
    const int lane = threadIdx.x & 31, rw = threadIdx.x >> 5;
    const float* ib = img + (b << 16);
    float*       tb = imT + (b << 16);
#pragma unroll
    for (int p = 0; p < 4; ++p) {
        int row = rw + (p << 3);
        tl[row][lane] = ib[((y0 + row) << 8) + x0 + lane];
    }
    __syncthreads();
#pragma unroll
    for (int p = 0; p < 4; ++p) {
        int row = rw + (p << 3);
        tb[((x0 + row) << 8) + y0 + lane] = tl[lane][row];
    }
}

__global__ __launch_bounds__(512, 8) void radon_k(const float* __restrict__ img,
                                                  const float* __restrict__ imT,
                                                  float* __restrict__ ws2) {
    __shared__ f16x2 lds2[LDSW];
    const int tid = threadIdx.x;
    const int bx  = blockIdx.x;                   // 2048 = b(4) x g(64) x q(8)
    const int q = bx & 7, g = (bx >> 3) & 63, b = bx >> 9;
    const int rbase = (q << 5) - 2;
    const bool colC = (g >= 16) && (g < 48);      // a in [128,384): column slabs
    const float* src = (colC ? imT : img) + (b << 16);

    // ---- stage slab, coalesced reads, column-major LDS write (stride SR odd)
    for (int u = tid; u < LDSW; u += 512) {
        int rr = u / NC;
        int X  = u - rr * NC;
        int r  = rbase + rr;
        float va = 0.f, vb = 0.f;
        if ((unsigned)r < 256u) {
            const float* rp = src + (r << 8);
            if (X > 0)   va = rp[X - 1];
            if (X < 256) vb = rp[X];
        }
        f16x2 h2; h2.x = (f16)va; h2.y = (f16)vb;
        lds2[X * SR + rr] = h2;
    }
    __syncthreads();

    const int   w   = tid & 255, sub = tid >> 8;  // angle uniform per wave
    const float xw  = (float)w - 127.5f;
    const float B0  = (q == 0) ? -1.25f  : (float)(q << 5);
    const float B1  = (q == 7) ? 257.25f : (float)((q << 5) + 32);

    for (int k = 0; k < 4; ++k) {
        const int j = (k << 1) | sub;
        const int a = (g << 3) | j;
        float sth, cth;
        sincosf((float)a * 6.1359231515425649e-3f, &sth, &cth);
        const float Ax = fmaf(cth, xw, fmaf(sth, -127.5f, 127.5f));
        const float Ay = fmaf(-sth, xw, fmaf(cth, -127.5f, 127.5f));
        // role assignment: col coord (pair dim, small slope) / row coord (slab dim)
        float cs, As, rs, Ar;
        if (colC) { cs = cth; As = Ay; rs = sth; Ar = Ax; }
        else      { cs = sth; As = Ax; rs = cth; Ar = Ay; }

        // ---- slab ownership on r(h)=Ar+h*rs in [B0,B1); |rs|>=0.707, exact
        // ceil/floor partition (adjacent q share identical boundary floats)
        const float invr = 1.0f / rs;
        const float tA = (B0 - Ar) * invr, tB = (B1 - Ar) * invr;
        int h0, h1;
        if (rs > 0.f) { h0 = (int)ceilf(tA);      h1 = (int)ceilf(tB) - 1; }
        else          { h0 = (int)floorf(tB) + 1; h1 = (int)floorf(tA);   }

        // ---- col validity v(h)=As+h*cs in (-1,256); cs signed, may be ~0
        if (cs != 0.f) {
            const float invc = 1.0f / cs;
            float ta = (-1.0f - As) * invc, tb = (256.0f - As) * invc;
            ta = fmaxf(fminf(ta, 400.f), -400.f);
            tb = fmaxf(fminf(tb, 400.f), -400.f);
            if (cs > 0.f) { h0 = max(h0, (int)ceilf(ta));      h1 = min(h1, (int)ceilf(tb) - 1); }
            else          { h0 = max(h0, (int)floorf(tb) + 1); h1 = min(h1, (int)floorf(ta));   }
        } else if (As <= -1.f || As >= 256.f) {
            h1 = h0 - 1;                          // constant col coord, out of range
        }
        h0 = max(h0, 0); h1 = min(h1, 255);

        float acc0 = 0.f, acc1 = 0.f;
        if (h0 <= h1) {
            const float h0f = (float)h0;
            float pcA = fmaf(h0f, cs, As + 1.0f);          // col coord + 1
            float prA = fmaf(h0f, rs, Ar - (float)rbase);  // slab-local row
            float pcB = pcA + cs, prB = prA + rs;
            const float cs2 = cs + cs, rs2 = rs + rs;
            const int n = h1 - h0 + 1;
            int i = 0;
            for (; i + 2 <= n; i += 2) {          // dual chains: 2 ds_read2 in flight
                SAMP(pcA, prA, acc0);
                SAMP(pcB, prB, acc1);
                pcA += cs2; prA += rs2; pcB += cs2; prB += rs2;
            }
            if (n & 1) SAMP(pcA, prA, acc0);
        }
        // always store (ws poisoned 0xAA); wave-coalesced 256B segments
        ws2[((((q << 2) + b) << 9) | a) * 256 + w] = acc0 + acc1;
    }
}

__global__ __launch_bounds__(256) void reduce_k(const float* __restrict__ ws2,
                                                float* __restrict__ out) {
    __shared__ float s[32][33];
    const int bx = blockIdx.x;                    // 512 = b(4) x at(16) x wt(8)
    const int wt = bx & 7, at = (bx >> 3) & 15, b = bx >> 7;
    const int a0 = at << 5, w0 = wt << 5;
    const int wl = threadIdx.x & 31, r8 = threadIdx.x >> 5;
#pragma unroll
    for (int p = 0; p < 4; ++p) {
        int ar = r8 + (p << 3);
        int a  = a0 + ar;
        float acc = 0.f;
#pragma unroll
        for (int qq = 0; qq < 8; ++qq)
            acc += ws2[(((((qq << 2) + b) << 9) | a) << 8) | (w0 + wl)];
        s[ar][wl] = acc;                          // s[a_local][w_local]
    }
    __syncthreads();
#pragma unroll
    for (int p = 0; p < 4; ++p) {
        int wr = r8 + (p << 3);
        out[(b << 17) | ((w0 + wr) << 9) | (a0 + wl)] = s[wl][wr];  // coalesced in a
    }
}

extern "C" void kernel_launch(void* const* d_in, const int* in_sizes, int n_in,
                              void* d_out, int out_size, void* d_ws, size_t ws_size,
                              hipStream_t stream) {
    const float* img = (const float*)d_in[0];
    float* out = (float*)d_out;
    float* imT = (float*)d_ws;                    // 1 MB
    float* ws2 = (float*)d_ws + (1 << 18);        // 16.8 MB: [q][b][a][w]
    transpose_k<<<dim3(256),  dim3(256), 0, stream>>>(img, imT);
    radon_k   <<<dim3(2048), dim3(512), 0, stream>>>(img, imT, ws2);
    reduce_k  <<<dim3(512),  dim3(256), 0, stream>>>(ws2, out);
}